// Round 6
// baseline (196.736 us; speedup 1.0000x reference)
//
#include <hip/hip_runtime.h>
#include <hip/hip_bf16.h>
#include <math.h>

#define NN 50000
#define NE 800000
#define ETOT (NE + NN)
#define LEAKY 0.2f
#define BN_EPS 1e-5f

#define NB 256      // dst buckets
#define BSZ 196     // nodes per bucket (256*196 = 50176 >= NN)
#define NBB 128     // binning blocks
#define EPB ((ETOT + NBB - 1) / NBB)

#define BN1 144   // 128 h1 cols + 4 es + 4 ed + 8 pad
#define BN2 48    // 40 h2 cols + es2 + ed2 + 6 pad

typedef unsigned short u16;
typedef unsigned int u32;
typedef short s16;
typedef __attribute__((ext_vector_type(8))) short bf16x8;
typedef __attribute__((ext_vector_type(4))) float f32x4;

__device__ __forceinline__ float bf2f(u32 u) {
    union { u32 i; float f; } x; x.i = u << 16; return x.f;
}
__device__ __forceinline__ u16 f2bf(float f) {
    __hip_bfloat16 b = __float2bfloat16(f);
    return *reinterpret_cast<u16*>(&b);
}

// ---- CSR build: bucket-local, write-combining friendly ----

__global__ __launch_bounds__(256) void k_binA(const int* __restrict__ ei,
                                              int* __restrict__ cnt) {
    __shared__ int hist[NB];
    int t = threadIdx.x;
    for (int i = t; i < NB; i += 256) hist[i] = 0;
    __syncthreads();
    int e0 = blockIdx.x * EPB, e1 = min(e0 + EPB, ETOT);
    for (int e = e0 + t; e < e1; e += 256) {
        int dst = (e < NE) ? ei[NE + e] : (e - NE);
        atomicAdd(&hist[dst / BSZ], 1);
    }
    __syncthreads();
    for (int b = t; b < NB; b += 256) cnt[b * NBB + blockIdx.x] = hist[b];
}

__global__ __launch_bounds__(256) void k_scanA(const int* __restrict__ in,
                                               int* __restrict__ out,
                                               int* __restrict__ bsums, int n) {
    __shared__ int sh[256];
    int t = threadIdx.x;
    int i = blockIdx.x * 256 + t;
    int v = (i < n) ? in[i] : 0;
    sh[t] = v;
    __syncthreads();
    #pragma unroll
    for (int off = 1; off < 256; off <<= 1) {
        int u = (t >= off) ? sh[t - off] : 0;
        __syncthreads();
        sh[t] += u;
        __syncthreads();
    }
    if (i < n) out[i] = sh[t] - v;
    if (t == 255) bsums[blockIdx.x] = sh[t];
}

__global__ __launch_bounds__(256) void k_scanB(int* __restrict__ bsums, int nb) {
    __shared__ int sh[256];
    int t = threadIdx.x;
    int v = (t < nb) ? bsums[t] : 0;
    sh[t] = v;
    __syncthreads();
    #pragma unroll
    for (int off = 1; off < 256; off <<= 1) {
        int u = (t >= off) ? sh[t - off] : 0;
        __syncthreads();
        sh[t] += u;
        __syncthreads();
    }
    if (t < nb) bsums[t] = sh[t] - v;
}

__global__ void k_scanC(int* __restrict__ out, const int* __restrict__ bsums, int n) {
    int i = blockIdx.x * blockDim.x + threadIdx.x;
    if (i < n) out[i] += bsums[i >> 8];
}

__global__ __launch_bounds__(256) void k_binB(const int* __restrict__ ei,
                                              const int* __restrict__ excl,
                                              u32* __restrict__ packed) {
    __shared__ int cur[NB];
    int t = threadIdx.x;
    for (int b = t; b < NB; b += 256) cur[b] = excl[b * NBB + blockIdx.x];
    __syncthreads();
    int e0 = blockIdx.x * EPB, e1 = min(e0 + EPB, ETOT);
    for (int e = e0 + t; e < e1; e += 256) {
        int src, dst;
        if (e < NE) { src = ei[e]; dst = ei[NE + e]; }
        else        { src = e - NE; dst = e - NE; }
        int pos = atomicAdd(&cur[dst / BSZ], 1);
        packed[pos] = ((u32)src << 16) | (u32)dst;
    }
}

__global__ __launch_bounds__(256) void k_binC(const u32* __restrict__ packed,
                                              const int* __restrict__ excl,
                                              int* __restrict__ offsets,
                                              int* __restrict__ ssrc) {
    __shared__ int hist[256];
    __shared__ int sc[256];
    __shared__ int cur[256];
    int b = blockIdx.x, t = threadIdx.x;
    int n0 = b * BSZ;
    int base = excl[b * NBB];
    int next = (b < NB - 1) ? excl[(b + 1) * NBB] : ETOT;
    int total = next - base;
    hist[t] = 0;
    __syncthreads();
    for (int i = t; i < total; i += 256) {
        int dst = (int)(packed[base + i] & 0xffffu);
        atomicAdd(&hist[dst - n0], 1);
    }
    __syncthreads();
    int v = hist[t];
    sc[t] = v;
    __syncthreads();
    #pragma unroll
    for (int off = 1; off < 256; off <<= 1) {
        int u = (t >= off) ? sc[t - off] : 0;
        __syncthreads();
        sc[t] += u;
        __syncthreads();
    }
    int exl = sc[t] - v;
    int node = n0 + t;
    if (t <= BSZ && node <= NN) {
        if (t < BSZ || node == NN) offsets[node] = base + exl;
    }
    cur[t] = exl;
    __syncthreads();
    for (int i = t; i < total; i += 256) {
        u32 pv = packed[base + i];
        int dst = (int)(pv & 0xffffu);
        int pos = atomicAdd(&cur[dst - n0], 1);
        ssrc[base + pos] = (int)(pv >> 16);
    }
}

// ---- weight prep (fused attention-coefficient columns) ----
__global__ void k_prep(const float* __restrict__ W1, const float* __restrict__ a1s,
                       const float* __restrict__ a1d, const float* __restrict__ W2,
                       const float* __restrict__ a2s, const float* __restrict__ a2d,
                       u16* __restrict__ Wt1, u16* __restrict__ Wt2) {
    int tid = blockIdx.x * blockDim.x + threadIdx.x;
    int nth = gridDim.x * blockDim.x;
    for (int idx = tid; idx < BN1 * 128; idx += nth) {
        int n = idx >> 7, k = idx & 127;
        float v = 0.f;
        if (n < 128) v = W1[k * 128 + n];
        else if (n < 132) {
            int h = n - 128; float s = 0.f;
            for (int c = 0; c < 32; ++c) s += W1[k * 128 + h * 32 + c] * a1s[h * 32 + c];
            v = s;
        } else if (n < 136) {
            int h = n - 132; float s = 0.f;
            for (int c = 0; c < 32; ++c) s += W1[k * 128 + h * 32 + c] * a1d[h * 32 + c];
            v = s;
        }
        Wt1[idx] = f2bf(v);
    }
    for (int idx = tid; idx < BN2 * 128; idx += nth) {
        int n = idx >> 7, k = idx & 127;
        float v = 0.f;
        if (n < 40) v = W2[k * 40 + n];
        else if (n == 40) { float s = 0.f; for (int c = 0; c < 40; ++c) s += W2[k * 40 + c] * a2s[c]; v = s; }
        else if (n == 41) { float s = 0.f; for (int c = 0; c < 40; ++c) s += W2[k * 40 + c] * a2d[c]; v = s; }
        Wt2[idx] = f2bf(v);
    }
}

// MFMA GEMM layer 1: h1b[NN,128] bf16 + es1/ed1[NN,4] fp32, from x fp32.
__global__ __launch_bounds__(256) void k_mm1(const float* __restrict__ x,
                                             const u16* __restrict__ Wt1,
                                             u16* __restrict__ h1b,
                                             float* __restrict__ es1,
                                             float* __restrict__ ed1) {
    __shared__ __align__(16) s16 As[128 * 128];
    __shared__ __align__(16) s16 Bs[BN1 * 128];
    int t = threadIdx.x;
    int row0 = blockIdx.x * 128;
    #pragma unroll
    for (int i = 0; i < 16; ++i) {
        int c = t + i * 256;
        int r = c >> 5, k0 = (c & 31) * 4;
        float4 v = make_float4(0.f, 0.f, 0.f, 0.f);
        int row = row0 + r;
        if (row < NN) v = *(const float4*)&x[(size_t)row * 128 + k0];
        u16 pk[4] = {f2bf(v.x), f2bf(v.y), f2bf(v.z), f2bf(v.w)};
        int byte = (r * 256 + k0 * 2) ^ ((r & 7) << 4);
        *(uint2*)((char*)As + byte) = *(uint2*)pk;
    }
    #pragma unroll
    for (int i = 0; i < 9; ++i) {
        int c = t + i * 256;
        int n = c >> 4, k0 = (c & 15) * 8;
        uint4 v = *(const uint4*)&Wt1[n * 128 + k0];
        int byte = (n * 256 + k0 * 2) ^ ((n & 7) << 4);
        *(uint4*)((char*)Bs + byte) = v;
    }
    __syncthreads();
    int wave = t >> 6, lane = t & 63;
    int lr = lane & 15, lq = lane >> 4;
    int wrow = wave * 32;
    f32x4 acc[2][9];
    #pragma unroll
    for (int a = 0; a < 2; ++a)
        #pragma unroll
        for (int b = 0; b < 9; ++b) acc[a][b] = (f32x4){0.f, 0.f, 0.f, 0.f};
    #pragma unroll
    for (int ks = 0; ks < 4; ++ks) {
        int kb = ks * 32 + lq * 8;
        bf16x8 af[2];
        #pragma unroll
        for (int rb = 0; rb < 2; ++rb) {
            int r = wrow + rb * 16 + lr;
            int byte = (r * 256 + kb * 2) ^ ((r & 7) << 4);
            af[rb] = *(bf16x8*)((char*)As + byte);
        }
        #pragma unroll
        for (int cb = 0; cb < 9; ++cb) {
            int n = cb * 16 + lr;
            int byte = (n * 256 + kb * 2) ^ ((n & 7) << 4);
            bf16x8 bfr = *(bf16x8*)((char*)Bs + byte);
            acc[0][cb] = __builtin_amdgcn_mfma_f32_16x16x32_bf16(af[0], bfr, acc[0][cb], 0, 0, 0);
            acc[1][cb] = __builtin_amdgcn_mfma_f32_16x16x32_bf16(af[1], bfr, acc[1][cb], 0, 0, 0);
        }
    }
    #pragma unroll
    for (int rb = 0; rb < 2; ++rb) {
        #pragma unroll
        for (int cb = 0; cb < 9; ++cb) {
            #pragma unroll
            for (int r = 0; r < 4; ++r) {
                int row = row0 + wrow + rb * 16 + lq * 4 + r;
                int col = cb * 16 + lr;
                if (row < NN) {
                    float v = acc[rb][cb][r];
                    if (col < 128) h1b[(size_t)row * 128 + col] = f2bf(v);
                    else if (col < 132) es1[row * 4 + (col - 128)] = v;
                    else if (col < 136) ed1[row * 4 + (col - 132)] = v;
                }
            }
        }
    }
}

// MFMA GEMM layer 2: h2[NN,40] fp32 + es2/ed2[NN] fp32, from hbnb bf16.
__global__ __launch_bounds__(256) void k_mm2(const u16* __restrict__ hbnb,
                                             const u16* __restrict__ Wt2,
                                             float* __restrict__ h2,
                                             float* __restrict__ es2,
                                             float* __restrict__ ed2) {
    __shared__ __align__(16) s16 As[128 * 128];
    __shared__ __align__(16) s16 Bs[BN2 * 128];
    int t = threadIdx.x;
    int row0 = blockIdx.x * 128;
    #pragma unroll
    for (int i = 0; i < 8; ++i) {
        int c = t + i * 256;
        int r = c >> 4, k0 = (c & 15) * 8;
        uint4 v = make_uint4(0, 0, 0, 0);
        int row = row0 + r;
        if (row < NN) v = *(const uint4*)&hbnb[(size_t)row * 128 + k0];
        int byte = (r * 256 + k0 * 2) ^ ((r & 7) << 4);
        *(uint4*)((char*)As + byte) = v;
    }
    #pragma unroll
    for (int i = 0; i < 3; ++i) {
        int c = t + i * 256;
        int n = c >> 4, k0 = (c & 15) * 8;
        uint4 v = *(const uint4*)&Wt2[n * 128 + k0];
        int byte = (n * 256 + k0 * 2) ^ ((n & 7) << 4);
        *(uint4*)((char*)Bs + byte) = v;
    }
    __syncthreads();
    int wave = t >> 6, lane = t & 63;
    int lr = lane & 15, lq = lane >> 4;
    int wrow = wave * 32;
    f32x4 acc[2][3];
    #pragma unroll
    for (int a = 0; a < 2; ++a)
        #pragma unroll
        for (int b = 0; b < 3; ++b) acc[a][b] = (f32x4){0.f, 0.f, 0.f, 0.f};
    #pragma unroll
    for (int ks = 0; ks < 4; ++ks) {
        int kb = ks * 32 + lq * 8;
        bf16x8 af[2];
        #pragma unroll
        for (int rb = 0; rb < 2; ++rb) {
            int r = wrow + rb * 16 + lr;
            int byte = (r * 256 + kb * 2) ^ ((r & 7) << 4);
            af[rb] = *(bf16x8*)((char*)As + byte);
        }
        #pragma unroll
        for (int cb = 0; cb < 3; ++cb) {
            int n = cb * 16 + lr;
            int byte = (n * 256 + kb * 2) ^ ((n & 7) << 4);
            bf16x8 bfr = *(bf16x8*)((char*)Bs + byte);
            acc[0][cb] = __builtin_amdgcn_mfma_f32_16x16x32_bf16(af[0], bfr, acc[0][cb], 0, 0, 0);
            acc[1][cb] = __builtin_amdgcn_mfma_f32_16x16x32_bf16(af[1], bfr, acc[1][cb], 0, 0, 0);
        }
    }
    #pragma unroll
    for (int rb = 0; rb < 2; ++rb) {
        #pragma unroll
        for (int cb = 0; cb < 3; ++cb) {
            #pragma unroll
            for (int r = 0; r < 4; ++r) {
                int row = row0 + wrow + rb * 16 + lq * 4 + r;
                int col = cb * 16 + lr;
                if (row < NN) {
                    float v = acc[rb][cb][r];
                    if (col < 40) h2[(size_t)row * 40 + col] = v;
                    else if (col == 40) es2[row] = v;
                    else if (col == 41) ed2[row] = v;
                }
            }
        }
    }
}

// layer-1 aggregation: lane-parallel edge weights + shfl broadcast
__global__ __launch_bounds__(256) void k_agg1(
        const u16* __restrict__ h1b, const float* __restrict__ es,
        const float* __restrict__ ed, const int* __restrict__ offsets,
        const int* __restrict__ ssrc, const float* __restrict__ b1,
        const float* __restrict__ gamma, const float* __restrict__ beta,
        const float* __restrict__ mean, const float* __restrict__ var,
        u16* __restrict__ hbnb) {
    int node = blockIdx.x * 4 + (threadIdx.x >> 6);
    if (node >= NN) return;
    int l = threadIdx.x & 63;
    int head = l >> 4;
    int lr16 = l & 15;
    int p0 = offsets[node], p1 = offsets[node + 1];
    float edv = ed[node * 4 + head];
    float s = 0.f, acc0 = 0.f, acc1 = 0.f;
    for (int base = p0; base < p1; base += 64) {
        int cnt = min(64, p1 - base);
        int myidx = (l < cnt) ? ssrc[base + l] : 0;
        // lane l computes softmax weight of edge q*16+(l&15) for ITS head
        float mw0 = 0.f, mw1 = 0.f, mw2 = 0.f, mw3 = 0.f;
        {
            int j0 = lr16;
            int i0 = __shfl(myidx, j0);
            if (j0 < cnt) {
                float e = es[i0 * 4 + head] + edv;
                e = e > 0.f ? e : LEAKY * e;
                mw0 = __expf(e);
            }
            if (cnt > 16) {
                int j1 = 16 + lr16;
                int i1 = __shfl(myidx, j1);
                if (j1 < cnt) {
                    float e = es[i1 * 4 + head] + edv;
                    e = e > 0.f ? e : LEAKY * e;
                    mw1 = __expf(e);
                }
            }
            if (cnt > 32) {
                int j2 = 32 + lr16;
                int i2 = __shfl(myidx, j2);
                if (j2 < cnt) {
                    float e = es[i2 * 4 + head] + edv;
                    e = e > 0.f ? e : LEAKY * e;
                    mw2 = __expf(e);
                }
            }
            if (cnt > 48) {
                int j3 = 48 + lr16;
                int i3 = __shfl(myidx, j3);
                if (j3 < cnt) {
                    float e = es[i3 * 4 + head] + edv;
                    e = e > 0.f ? e : LEAKY * e;
                    mw3 = __expf(e);
                }
            }
        }
        // denominator: reduce within the 16-lane head group
        float ps = (mw0 + mw1) + (mw2 + mw3);
        ps += __shfl_xor(ps, 1);
        ps += __shfl_xor(ps, 2);
        ps += __shfl_xor(ps, 4);
        ps += __shfl_xor(ps, 8);
        s += ps;
        // weighted gather-accumulate; weight of edge j lives at lane (head<<4)|(j&15)
        #pragma unroll 16
        for (int r = 0; r < 16; ++r) {
            if (r >= cnt) break;
            int sj = __shfl(myidx, r);
            float xw = __shfl(mw0, (head << 4) | r);
            u32 w = *(const u32*)&h1b[(size_t)sj * 128 + 2 * l];
            acc0 = fmaf(xw, bf2f(w & 0xffffu), acc0);
            acc1 = fmaf(xw, bf2f(w >> 16), acc1);
        }
        if (cnt > 16) {
            #pragma unroll 16
            for (int r = 0; r < 16; ++r) {
                int j = 16 + r;
                if (j >= cnt) break;
                int sj = __shfl(myidx, j);
                float xw = __shfl(mw1, (head << 4) | r);
                u32 w = *(const u32*)&h1b[(size_t)sj * 128 + 2 * l];
                acc0 = fmaf(xw, bf2f(w & 0xffffu), acc0);
                acc1 = fmaf(xw, bf2f(w >> 16), acc1);
            }
        }
        if (cnt > 32) {
            #pragma unroll 16
            for (int r = 0; r < 16; ++r) {
                int j = 32 + r;
                if (j >= cnt) break;
                int sj = __shfl(myidx, j);
                float xw = __shfl(mw2, (head << 4) | r);
                u32 w = *(const u32*)&h1b[(size_t)sj * 128 + 2 * l];
                acc0 = fmaf(xw, bf2f(w & 0xffffu), acc0);
                acc1 = fmaf(xw, bf2f(w >> 16), acc1);
            }
        }
        if (cnt > 48) {
            #pragma unroll 16
            for (int r = 0; r < 16; ++r) {
                int j = 48 + r;
                if (j >= cnt) break;
                int sj = __shfl(myidx, j);
                float xw = __shfl(mw3, (head << 4) | r);
                u32 w = *(const u32*)&h1b[(size_t)sj * 128 + 2 * l];
                acc0 = fmaf(xw, bf2f(w & 0xffffu), acc0);
                acc1 = fmaf(xw, bf2f(w >> 16), acc1);
            }
        }
    }
    float inv = 1.f / s;
    int i0 = 2 * l, i1 = 2 * l + 1;
    float o0 = acc0 * inv + b1[i0];
    float o1 = acc1 * inv + b1[i1];
    o0 = (o0 - mean[i0]) * rsqrtf(var[i0] + BN_EPS) * gamma[i0] + beta[i0];
    o1 = (o1 - mean[i1]) * rsqrtf(var[i1] + BN_EPS) * gamma[i1] + beta[i1];
    o0 = o0 > 0.f ? o0 : __expf(o0) - 1.f;
    o1 = o1 > 0.f ? o1 : __expf(o1) - 1.f;
    u32 pk = (u32)f2bf(o0) | ((u32)f2bf(o1) << 16);
    *(u32*)&hbnb[(size_t)node * 128 + 2 * l] = pk;
}

// layer-2 aggregation: lane-parallel weights + shfl broadcast + log_softmax
__global__ __launch_bounds__(256) void k_agg2(
        const float* __restrict__ h2, const float* __restrict__ es,
        const float* __restrict__ ed, const int* __restrict__ offsets,
        const int* __restrict__ ssrc, const float* __restrict__ b2,
        float* __restrict__ out) {
    int node = blockIdx.x * 4 + (threadIdx.x >> 6);
    if (node >= NN) return;
    int l = threadIdx.x & 63;
    int p0 = offsets[node], p1 = offsets[node + 1];
    float edv = ed[node];
    float s = 0.f, acc = 0.f;
    bool pay = (l < 40);
    for (int base = p0; base < p1; base += 64) {
        int cnt = min(64, p1 - base);
        int myidx = (l < cnt) ? ssrc[base + l] : 0;
        float mw = 0.f;
        if (l < cnt) {
            float e = es[myidx] + edv;
            e = e > 0.f ? e : LEAKY * e;
            mw = __expf(e);
        }
        float ps = mw;
        #pragma unroll
        for (int off = 1; off < 64; off <<= 1) ps += __shfl_xor(ps, off);
        s += ps;
        #pragma unroll 4
        for (int j = 0; j < cnt; ++j) {
            int sj = __shfl(myidx, j);
            float xw = __shfl(mw, j);
            float hv = pay ? h2[(size_t)sj * 40 + l] : 0.f;
            acc = fmaf(xw, hv, acc);
        }
    }
    float v = acc / s + (pay ? b2[l] : 0.f);
    float mv = pay ? v : -1e30f;
    #pragma unroll
    for (int off = 1; off < 64; off <<= 1) mv = fmaxf(mv, __shfl_xor(mv, off));
    float ex = pay ? __expf(v - mv) : 0.f;
    #pragma unroll
    for (int off = 1; off < 64; off <<= 1) ex += __shfl_xor(ex, off);
    if (pay) out[(size_t)node * 40 + l] = v - mv - __logf(ex);
}

extern "C" void kernel_launch(void* const* d_in, const int* in_sizes, int n_in,
                              void* d_out, int out_size, void* d_ws, size_t ws_size,
                              hipStream_t stream) {
    const float* x   = (const float*)d_in[0];
    const int*   ei  = (const int*)d_in[1];
    const float* W1  = (const float*)d_in[2];
    const float* a1s = (const float*)d_in[3];
    const float* a1d = (const float*)d_in[4];
    const float* b1  = (const float*)d_in[5];
    const float* bng = (const float*)d_in[6];
    const float* bnb = (const float*)d_in[7];
    const float* bnm = (const float*)d_in[8];
    const float* bnv = (const float*)d_in[9];
    const float* W2  = (const float*)d_in[10];
    const float* a2s = (const float*)d_in[11];
    const float* a2d = (const float*)d_in[12];
    const float* b2  = (const float*)d_in[13];
    float* out = (float*)d_out;

    char* ws = (char*)d_ws;
    size_t off = 0;
    auto alloc = [&](size_t bytes) -> void* {
        void* p = ws + off;
        off = (off + bytes + 255) & ~(size_t)255;
        return p;
    };
    int*   cntb     = (int*)alloc((size_t)NB * NBB * 4);
    int*   excl     = (int*)alloc((size_t)NB * NBB * 4);
    int*   bsums    = (int*)alloc((size_t)NBB * 4);
    int*   offsets  = (int*)alloc((size_t)(NN + 1) * 4);
    u32*   packed   = (u32*)alloc((size_t)ETOT * 4);
    int*   ssrc     = (int*)alloc((size_t)ETOT * 4);
    u16*   Wt1      = (u16*)alloc((size_t)BN1 * 128 * 2);
    u16*   Wt2      = (u16*)alloc((size_t)BN2 * 128 * 2);
    u16*   h1b      = (u16*)alloc((size_t)NN * 128 * 2);
    float* es1      = (float*)alloc((size_t)NN * 4 * 4);
    float* ed1      = (float*)alloc((size_t)NN * 4 * 4);
    u16*   hbnb     = (u16*)alloc((size_t)NN * 128 * 2);
    float* h2       = (float*)alloc((size_t)NN * 40 * 4);
    float* es2      = (float*)alloc((size_t)NN * 4);
    float* ed2      = (float*)alloc((size_t)NN * 4);

    const int nscan = NB * NBB;  // 32768
    k_prep<<<80, 256, 0, stream>>>(W1, a1s, a1d, W2, a2s, a2d, Wt1, Wt2);
    k_binA<<<NBB, 256, 0, stream>>>(ei, cntb);
    k_scanA<<<nscan / 256, 256, 0, stream>>>(cntb, excl, bsums, nscan);
    k_scanB<<<1, 256, 0, stream>>>(bsums, NBB);
    k_scanC<<<nscan / 256, 256, 0, stream>>>(excl, bsums, nscan);
    k_binB<<<NBB, 256, 0, stream>>>(ei, excl, packed);
    k_binC<<<NB, 256, 0, stream>>>(packed, excl, offsets, ssrc);
    k_mm1<<<(NN + 127) / 128, 256, 0, stream>>>(x, Wt1, h1b, es1, ed1);
    k_agg1<<<(NN + 3) / 4, 256, 0, stream>>>(h1b, es1, ed1, offsets, ssrc,
                                             b1, bng, bnb, bnm, bnv, hbnb);
    k_mm2<<<(NN + 127) / 128, 256, 0, stream>>>(hbnb, Wt2, h2, es2, ed2);
    k_agg2<<<(NN + 3) / 4, 256, 0, stream>>>(h2, es2, ed2, offsets, ssrc, b2, out);
}

// Round 7
// 144.963 us; speedup vs baseline: 1.3571x; 1.3571x over previous
//
#include <hip/hip_runtime.h>
#include <hip/hip_bf16.h>
#include <math.h>

#define NN 50000
#define NE 800000
#define ETOT (NE + NN)
#define LEAKY 0.2f
#define BN_EPS 1e-5f

#define NB 256      // dst buckets
#define BSZ 196     // nodes per bucket (256*196 = 50176 >= NN)
#define NBB 128     // binning blocks
#define EPB ((ETOT + NBB - 1) / NBB)

#define BN1 144   // 128 h1 cols + 4 es + 4 ed + 8 pad
#define BN2 48    // 40 h2 cols + es2 + ed2 + 6 pad

typedef unsigned short u16;
typedef unsigned int u32;
typedef short s16;
typedef __attribute__((ext_vector_type(8))) short bf16x8;
typedef __attribute__((ext_vector_type(4))) float f32x4;

__device__ __forceinline__ float bf2f(u32 u) {
    union { u32 i; float f; } x; x.i = u << 16; return x.f;
}
__device__ __forceinline__ u16 f2bf(float f) {
    __hip_bfloat16 b = __float2bfloat16(f);
    return *reinterpret_cast<u16*>(&b);
}

// ---- CSR build: bucket-local, write-combining friendly ----

__global__ __launch_bounds__(256) void k_binA(const int* __restrict__ ei,
                                              int* __restrict__ cnt) {
    __shared__ int hist[NB];
    int t = threadIdx.x;
    for (int i = t; i < NB; i += 256) hist[i] = 0;
    __syncthreads();
    int e0 = blockIdx.x * EPB, e1 = min(e0 + EPB, ETOT);
    for (int e = e0 + t; e < e1; e += 256) {
        int dst = (e < NE) ? ei[NE + e] : (e - NE);
        atomicAdd(&hist[dst / BSZ], 1);
    }
    __syncthreads();
    for (int b = t; b < NB; b += 256) cnt[b * NBB + blockIdx.x] = hist[b];
}

__global__ __launch_bounds__(256) void k_scanA(const int* __restrict__ in,
                                               int* __restrict__ out,
                                               int* __restrict__ bsums, int n) {
    __shared__ int sh[256];
    int t = threadIdx.x;
    int i = blockIdx.x * 256 + t;
    int v = (i < n) ? in[i] : 0;
    sh[t] = v;
    __syncthreads();
    #pragma unroll
    for (int off = 1; off < 256; off <<= 1) {
        int u = (t >= off) ? sh[t - off] : 0;
        __syncthreads();
        sh[t] += u;
        __syncthreads();
    }
    if (i < n) out[i] = sh[t] - v;
    if (t == 255) bsums[blockIdx.x] = sh[t];
}

__global__ __launch_bounds__(256) void k_scanB(int* __restrict__ bsums, int nb) {
    __shared__ int sh[256];
    int t = threadIdx.x;
    int v = (t < nb) ? bsums[t] : 0;
    sh[t] = v;
    __syncthreads();
    #pragma unroll
    for (int off = 1; off < 256; off <<= 1) {
        int u = (t >= off) ? sh[t - off] : 0;
        __syncthreads();
        sh[t] += u;
        __syncthreads();
    }
    if (t < nb) bsums[t] = sh[t] - v;
}

__global__ void k_scanC(int* __restrict__ out, const int* __restrict__ bsums, int n) {
    int i = blockIdx.x * blockDim.x + threadIdx.x;
    if (i < n) out[i] += bsums[i >> 8];
}

__global__ __launch_bounds__(256) void k_binB(const int* __restrict__ ei,
                                              const int* __restrict__ excl,
                                              u32* __restrict__ packed) {
    __shared__ int cur[NB];
    int t = threadIdx.x;
    for (int b = t; b < NB; b += 256) cur[b] = excl[b * NBB + blockIdx.x];
    __syncthreads();
    int e0 = blockIdx.x * EPB, e1 = min(e0 + EPB, ETOT);
    for (int e = e0 + t; e < e1; e += 256) {
        int src, dst;
        if (e < NE) { src = ei[e]; dst = ei[NE + e]; }
        else        { src = e - NE; dst = e - NE; }
        int pos = atomicAdd(&cur[dst / BSZ], 1);
        packed[pos] = ((u32)src << 16) | (u32)dst;
    }
}

__global__ __launch_bounds__(256) void k_binC(const u32* __restrict__ packed,
                                              const int* __restrict__ excl,
                                              int* __restrict__ offsets,
                                              int* __restrict__ ssrc) {
    __shared__ int hist[256];
    __shared__ int sc[256];
    __shared__ int cur[256];
    int b = blockIdx.x, t = threadIdx.x;
    int n0 = b * BSZ;
    int base = excl[b * NBB];
    int next = (b < NB - 1) ? excl[(b + 1) * NBB] : ETOT;
    int total = next - base;
    hist[t] = 0;
    __syncthreads();
    for (int i = t; i < total; i += 256) {
        int dst = (int)(packed[base + i] & 0xffffu);
        atomicAdd(&hist[dst - n0], 1);
    }
    __syncthreads();
    int v = hist[t];
    sc[t] = v;
    __syncthreads();
    #pragma unroll
    for (int off = 1; off < 256; off <<= 1) {
        int u = (t >= off) ? sc[t - off] : 0;
        __syncthreads();
        sc[t] += u;
        __syncthreads();
    }
    int exl = sc[t] - v;
    int node = n0 + t;
    if (t <= BSZ && node <= NN) {
        if (t < BSZ || node == NN) offsets[node] = base + exl;
    }
    cur[t] = exl;
    __syncthreads();
    for (int i = t; i < total; i += 256) {
        u32 pv = packed[base + i];
        int dst = (int)(pv & 0xffffu);
        int pos = atomicAdd(&cur[dst - n0], 1);
        ssrc[base + pos] = (int)(pv >> 16);
    }
}

// ---- weight prep (fused attention-coefficient columns) ----
__global__ void k_prep(const float* __restrict__ W1, const float* __restrict__ a1s,
                       const float* __restrict__ a1d, const float* __restrict__ W2,
                       const float* __restrict__ a2s, const float* __restrict__ a2d,
                       u16* __restrict__ Wt1, u16* __restrict__ Wt2) {
    int tid = blockIdx.x * blockDim.x + threadIdx.x;
    int nth = gridDim.x * blockDim.x;
    for (int idx = tid; idx < BN1 * 128; idx += nth) {
        int n = idx >> 7, k = idx & 127;
        float v = 0.f;
        if (n < 128) v = W1[k * 128 + n];
        else if (n < 132) {
            int h = n - 128; float s = 0.f;
            for (int c = 0; c < 32; ++c) s += W1[k * 128 + h * 32 + c] * a1s[h * 32 + c];
            v = s;
        } else if (n < 136) {
            int h = n - 132; float s = 0.f;
            for (int c = 0; c < 32; ++c) s += W1[k * 128 + h * 32 + c] * a1d[h * 32 + c];
            v = s;
        }
        Wt1[idx] = f2bf(v);
    }
    for (int idx = tid; idx < BN2 * 128; idx += nth) {
        int n = idx >> 7, k = idx & 127;
        float v = 0.f;
        if (n < 40) v = W2[k * 40 + n];
        else if (n == 40) { float s = 0.f; for (int c = 0; c < 40; ++c) s += W2[k * 40 + c] * a2s[c]; v = s; }
        else if (n == 41) { float s = 0.f; for (int c = 0; c < 40; ++c) s += W2[k * 40 + c] * a2d[c]; v = s; }
        Wt2[idx] = f2bf(v);
    }
}

// MFMA GEMM layer 1: h1b[NN,128] bf16 + es1/ed1[NN,4] fp32, from x fp32.
__global__ __launch_bounds__(256) void k_mm1(const float* __restrict__ x,
                                             const u16* __restrict__ Wt1,
                                             u16* __restrict__ h1b,
                                             float* __restrict__ es1,
                                             float* __restrict__ ed1) {
    __shared__ __align__(16) s16 As[128 * 128];
    __shared__ __align__(16) s16 Bs[BN1 * 128];
    int t = threadIdx.x;
    int row0 = blockIdx.x * 128;
    #pragma unroll
    for (int i = 0; i < 16; ++i) {
        int c = t + i * 256;
        int r = c >> 5, k0 = (c & 31) * 4;
        float4 v = make_float4(0.f, 0.f, 0.f, 0.f);
        int row = row0 + r;
        if (row < NN) v = *(const float4*)&x[(size_t)row * 128 + k0];
        u16 pk[4] = {f2bf(v.x), f2bf(v.y), f2bf(v.z), f2bf(v.w)};
        int byte = (r * 256 + k0 * 2) ^ ((r & 7) << 4);
        *(uint2*)((char*)As + byte) = *(uint2*)pk;
    }
    #pragma unroll
    for (int i = 0; i < 9; ++i) {
        int c = t + i * 256;
        int n = c >> 4, k0 = (c & 15) * 8;
        uint4 v = *(const uint4*)&Wt1[n * 128 + k0];
        int byte = (n * 256 + k0 * 2) ^ ((n & 7) << 4);
        *(uint4*)((char*)Bs + byte) = v;
    }
    __syncthreads();
    int wave = t >> 6, lane = t & 63;
    int lr = lane & 15, lq = lane >> 4;
    int wrow = wave * 32;
    f32x4 acc[2][9];
    #pragma unroll
    for (int a = 0; a < 2; ++a)
        #pragma unroll
        for (int b = 0; b < 9; ++b) acc[a][b] = (f32x4){0.f, 0.f, 0.f, 0.f};
    #pragma unroll
    for (int ks = 0; ks < 4; ++ks) {
        int kb = ks * 32 + lq * 8;
        bf16x8 af[2];
        #pragma unroll
        for (int rb = 0; rb < 2; ++rb) {
            int r = wrow + rb * 16 + lr;
            int byte = (r * 256 + kb * 2) ^ ((r & 7) << 4);
            af[rb] = *(bf16x8*)((char*)As + byte);
        }
        #pragma unroll
        for (int cb = 0; cb < 9; ++cb) {
            int n = cb * 16 + lr;
            int byte = (n * 256 + kb * 2) ^ ((n & 7) << 4);
            bf16x8 bfr = *(bf16x8*)((char*)Bs + byte);
            acc[0][cb] = __builtin_amdgcn_mfma_f32_16x16x32_bf16(af[0], bfr, acc[0][cb], 0, 0, 0);
            acc[1][cb] = __builtin_amdgcn_mfma_f32_16x16x32_bf16(af[1], bfr, acc[1][cb], 0, 0, 0);
        }
    }
    #pragma unroll
    for (int rb = 0; rb < 2; ++rb) {
        #pragma unroll
        for (int cb = 0; cb < 9; ++cb) {
            #pragma unroll
            for (int r = 0; r < 4; ++r) {
                int row = row0 + wrow + rb * 16 + lq * 4 + r;
                int col = cb * 16 + lr;
                if (row < NN) {
                    float v = acc[rb][cb][r];
                    if (col < 128) h1b[(size_t)row * 128 + col] = f2bf(v);
                    else if (col < 132) es1[row * 4 + (col - 128)] = v;
                    else if (col < 136) ed1[row * 4 + (col - 132)] = v;
                }
            }
        }
    }
}

// MFMA GEMM layer 2: h2[NN,40] fp32 + es2/ed2[NN] fp32, from hbnb bf16.
__global__ __launch_bounds__(256) void k_mm2(const u16* __restrict__ hbnb,
                                             const u16* __restrict__ Wt2,
                                             float* __restrict__ h2,
                                             float* __restrict__ es2,
                                             float* __restrict__ ed2) {
    __shared__ __align__(16) s16 As[128 * 128];
    __shared__ __align__(16) s16 Bs[BN2 * 128];
    int t = threadIdx.x;
    int row0 = blockIdx.x * 128;
    #pragma unroll
    for (int i = 0; i < 8; ++i) {
        int c = t + i * 256;
        int r = c >> 4, k0 = (c & 15) * 8;
        uint4 v = make_uint4(0, 0, 0, 0);
        int row = row0 + r;
        if (row < NN) v = *(const uint4*)&hbnb[(size_t)row * 128 + k0];
        int byte = (r * 256 + k0 * 2) ^ ((r & 7) << 4);
        *(uint4*)((char*)As + byte) = v;
    }
    #pragma unroll
    for (int i = 0; i < 3; ++i) {
        int c = t + i * 256;
        int n = c >> 4, k0 = (c & 15) * 8;
        uint4 v = *(const uint4*)&Wt2[n * 128 + k0];
        int byte = (n * 256 + k0 * 2) ^ ((n & 7) << 4);
        *(uint4*)((char*)Bs + byte) = v;
    }
    __syncthreads();
    int wave = t >> 6, lane = t & 63;
    int lr = lane & 15, lq = lane >> 4;
    int wrow = wave * 32;
    f32x4 acc[2][3];
    #pragma unroll
    for (int a = 0; a < 2; ++a)
        #pragma unroll
        for (int b = 0; b < 3; ++b) acc[a][b] = (f32x4){0.f, 0.f, 0.f, 0.f};
    #pragma unroll
    for (int ks = 0; ks < 4; ++ks) {
        int kb = ks * 32 + lq * 8;
        bf16x8 af[2];
        #pragma unroll
        for (int rb = 0; rb < 2; ++rb) {
            int r = wrow + rb * 16 + lr;
            int byte = (r * 256 + kb * 2) ^ ((r & 7) << 4);
            af[rb] = *(bf16x8*)((char*)As + byte);
        }
        #pragma unroll
        for (int cb = 0; cb < 3; ++cb) {
            int n = cb * 16 + lr;
            int byte = (n * 256 + kb * 2) ^ ((n & 7) << 4);
            bf16x8 bfr = *(bf16x8*)((char*)Bs + byte);
            acc[0][cb] = __builtin_amdgcn_mfma_f32_16x16x32_bf16(af[0], bfr, acc[0][cb], 0, 0, 0);
            acc[1][cb] = __builtin_amdgcn_mfma_f32_16x16x32_bf16(af[1], bfr, acc[1][cb], 0, 0, 0);
        }
    }
    #pragma unroll
    for (int rb = 0; rb < 2; ++rb) {
        #pragma unroll
        for (int cb = 0; cb < 3; ++cb) {
            #pragma unroll
            for (int r = 0; r < 4; ++r) {
                int row = row0 + wrow + rb * 16 + lq * 4 + r;
                int col = cb * 16 + lr;
                if (row < NN) {
                    float v = acc[rb][cb][r];
                    if (col < 40) h2[(size_t)row * 40 + col] = v;
                    else if (col == 40) es2[row] = v;
                    else if (col == 41) ed2[row] = v;
                }
            }
        }
    }
}

// layer-1 aggregation (plain-exp softmax, 8-deep batched gather) + bias + BN + ELU
__global__ __launch_bounds__(256) void k_agg1(
        const u16* __restrict__ h1b, const float* __restrict__ es,
        const float* __restrict__ ed, const int* __restrict__ offsets,
        const int* __restrict__ ssrc, const float* __restrict__ b1,
        const float* __restrict__ gamma, const float* __restrict__ beta,
        const float* __restrict__ mean, const float* __restrict__ var,
        u16* __restrict__ hbnb) {
    int node = blockIdx.x * 4 + (threadIdx.x >> 6);
    if (node >= NN) return;
    int l = threadIdx.x & 63;
    int head = l >> 4;
    int p0 = offsets[node], p1 = offsets[node + 1];
    float edv = ed[node * 4 + head];
    float s = 0.f, acc0 = 0.f, acc1 = 0.f;
    for (int base = p0; base < p1; base += 64) {
        int cnt = min(64, p1 - base);
        int myidx = (l < cnt) ? ssrc[base + l] : 0;
        int j = 0;
        for (; j + 8 <= cnt; j += 8) {
            int s0 = __shfl(myidx, j);
            int s1 = __shfl(myidx, j + 1);
            int s2 = __shfl(myidx, j + 2);
            int s3 = __shfl(myidx, j + 3);
            int s4 = __shfl(myidx, j + 4);
            int s5 = __shfl(myidx, j + 5);
            int s6 = __shfl(myidx, j + 6);
            int s7 = __shfl(myidx, j + 7);
            u32 w0 = *(const u32*)&h1b[(size_t)s0 * 128 + 2 * l];
            u32 w1 = *(const u32*)&h1b[(size_t)s1 * 128 + 2 * l];
            u32 w2 = *(const u32*)&h1b[(size_t)s2 * 128 + 2 * l];
            u32 w3 = *(const u32*)&h1b[(size_t)s3 * 128 + 2 * l];
            u32 w4 = *(const u32*)&h1b[(size_t)s4 * 128 + 2 * l];
            u32 w5 = *(const u32*)&h1b[(size_t)s5 * 128 + 2 * l];
            u32 w6 = *(const u32*)&h1b[(size_t)s6 * 128 + 2 * l];
            u32 w7 = *(const u32*)&h1b[(size_t)s7 * 128 + 2 * l];
            float e0 = es[s0 * 4 + head] + edv;
            float e1 = es[s1 * 4 + head] + edv;
            float e2 = es[s2 * 4 + head] + edv;
            float e3 = es[s3 * 4 + head] + edv;
            float e4 = es[s4 * 4 + head] + edv;
            float e5 = es[s5 * 4 + head] + edv;
            float e6 = es[s6 * 4 + head] + edv;
            float e7 = es[s7 * 4 + head] + edv;
            e0 = e0 > 0.f ? e0 : LEAKY * e0;  float x0 = __expf(e0);
            e1 = e1 > 0.f ? e1 : LEAKY * e1;  float x1 = __expf(e1);
            e2 = e2 > 0.f ? e2 : LEAKY * e2;  float x2 = __expf(e2);
            e3 = e3 > 0.f ? e3 : LEAKY * e3;  float x3 = __expf(e3);
            e4 = e4 > 0.f ? e4 : LEAKY * e4;  float x4 = __expf(e4);
            e5 = e5 > 0.f ? e5 : LEAKY * e5;  float x5 = __expf(e5);
            e6 = e6 > 0.f ? e6 : LEAKY * e6;  float x6 = __expf(e6);
            e7 = e7 > 0.f ? e7 : LEAKY * e7;  float x7 = __expf(e7);
            s += ((x0 + x1) + (x2 + x3)) + ((x4 + x5) + (x6 + x7));
            acc0 = fmaf(x0, bf2f(w0 & 0xffffu), acc0);
            acc1 = fmaf(x0, bf2f(w0 >> 16), acc1);
            acc0 = fmaf(x1, bf2f(w1 & 0xffffu), acc0);
            acc1 = fmaf(x1, bf2f(w1 >> 16), acc1);
            acc0 = fmaf(x2, bf2f(w2 & 0xffffu), acc0);
            acc1 = fmaf(x2, bf2f(w2 >> 16), acc1);
            acc0 = fmaf(x3, bf2f(w3 & 0xffffu), acc0);
            acc1 = fmaf(x3, bf2f(w3 >> 16), acc1);
            acc0 = fmaf(x4, bf2f(w4 & 0xffffu), acc0);
            acc1 = fmaf(x4, bf2f(w4 >> 16), acc1);
            acc0 = fmaf(x5, bf2f(w5 & 0xffffu), acc0);
            acc1 = fmaf(x5, bf2f(w5 >> 16), acc1);
            acc0 = fmaf(x6, bf2f(w6 & 0xffffu), acc0);
            acc1 = fmaf(x6, bf2f(w6 >> 16), acc1);
            acc0 = fmaf(x7, bf2f(w7 & 0xffffu), acc0);
            acc1 = fmaf(x7, bf2f(w7 >> 16), acc1);
        }
        for (; j + 4 <= cnt; j += 4) {
            int s0 = __shfl(myidx, j);
            int s1 = __shfl(myidx, j + 1);
            int s2 = __shfl(myidx, j + 2);
            int s3 = __shfl(myidx, j + 3);
            u32 w0 = *(const u32*)&h1b[(size_t)s0 * 128 + 2 * l];
            u32 w1 = *(const u32*)&h1b[(size_t)s1 * 128 + 2 * l];
            u32 w2 = *(const u32*)&h1b[(size_t)s2 * 128 + 2 * l];
            u32 w3 = *(const u32*)&h1b[(size_t)s3 * 128 + 2 * l];
            float e0 = es[s0 * 4 + head] + edv;
            float e1 = es[s1 * 4 + head] + edv;
            float e2 = es[s2 * 4 + head] + edv;
            float e3 = es[s3 * 4 + head] + edv;
            e0 = e0 > 0.f ? e0 : LEAKY * e0;  float x0 = __expf(e0);
            e1 = e1 > 0.f ? e1 : LEAKY * e1;  float x1 = __expf(e1);
            e2 = e2 > 0.f ? e2 : LEAKY * e2;  float x2 = __expf(e2);
            e3 = e3 > 0.f ? e3 : LEAKY * e3;  float x3 = __expf(e3);
            s += (x0 + x1) + (x2 + x3);
            acc0 = fmaf(x0, bf2f(w0 & 0xffffu), acc0);
            acc1 = fmaf(x0, bf2f(w0 >> 16), acc1);
            acc0 = fmaf(x1, bf2f(w1 & 0xffffu), acc0);
            acc1 = fmaf(x1, bf2f(w1 >> 16), acc1);
            acc0 = fmaf(x2, bf2f(w2 & 0xffffu), acc0);
            acc1 = fmaf(x2, bf2f(w2 >> 16), acc1);
            acc0 = fmaf(x3, bf2f(w3 & 0xffffu), acc0);
            acc1 = fmaf(x3, bf2f(w3 >> 16), acc1);
        }
        for (; j < cnt; ++j) {
            int s0 = __shfl(myidx, j);
            u32 w0 = *(const u32*)&h1b[(size_t)s0 * 128 + 2 * l];
            float e0 = es[s0 * 4 + head] + edv;
            e0 = e0 > 0.f ? e0 : LEAKY * e0;
            float x0 = __expf(e0);
            s += x0;
            acc0 = fmaf(x0, bf2f(w0 & 0xffffu), acc0);
            acc1 = fmaf(x0, bf2f(w0 >> 16), acc1);
        }
    }
    float inv = 1.f / s;
    int i0 = 2 * l, i1 = 2 * l + 1;
    float o0 = acc0 * inv + b1[i0];
    float o1 = acc1 * inv + b1[i1];
    o0 = (o0 - mean[i0]) * rsqrtf(var[i0] + BN_EPS) * gamma[i0] + beta[i0];
    o1 = (o1 - mean[i1]) * rsqrtf(var[i1] + BN_EPS) * gamma[i1] + beta[i1];
    o0 = o0 > 0.f ? o0 : __expf(o0) - 1.f;
    o1 = o1 > 0.f ? o1 : __expf(o1) - 1.f;
    u32 pk = (u32)f2bf(o0) | ((u32)f2bf(o1) << 16);
    *(u32*)&hbnb[(size_t)node * 128 + 2 * l] = pk;
}

// layer-2 aggregation (plain-exp softmax, 8-deep batched gather) + bias + log_softmax
__global__ __launch_bounds__(256) void k_agg2(
        const float* __restrict__ h2, const float* __restrict__ es,
        const float* __restrict__ ed, const int* __restrict__ offsets,
        const int* __restrict__ ssrc, const float* __restrict__ b2,
        float* __restrict__ out) {
    int node = blockIdx.x * 4 + (threadIdx.x >> 6);
    if (node >= NN) return;
    int l = threadIdx.x & 63;
    int p0 = offsets[node], p1 = offsets[node + 1];
    float edv = ed[node];
    float s = 0.f, acc = 0.f;
    bool pay = (l < 40);
    for (int base = p0; base < p1; base += 64) {
        int cnt = min(64, p1 - base);
        int myidx = (l < cnt) ? ssrc[base + l] : 0;
        int j = 0;
        for (; j + 8 <= cnt; j += 8) {
            int s0 = __shfl(myidx, j);
            int s1 = __shfl(myidx, j + 1);
            int s2 = __shfl(myidx, j + 2);
            int s3 = __shfl(myidx, j + 3);
            int s4 = __shfl(myidx, j + 4);
            int s5 = __shfl(myidx, j + 5);
            int s6 = __shfl(myidx, j + 6);
            int s7 = __shfl(myidx, j + 7);
            float h0 = pay ? h2[(size_t)s0 * 40 + l] : 0.f;
            float h1v = pay ? h2[(size_t)s1 * 40 + l] : 0.f;
            float h2v = pay ? h2[(size_t)s2 * 40 + l] : 0.f;
            float h3 = pay ? h2[(size_t)s3 * 40 + l] : 0.f;
            float h4 = pay ? h2[(size_t)s4 * 40 + l] : 0.f;
            float h5 = pay ? h2[(size_t)s5 * 40 + l] : 0.f;
            float h6 = pay ? h2[(size_t)s6 * 40 + l] : 0.f;
            float h7 = pay ? h2[(size_t)s7 * 40 + l] : 0.f;
            float e0 = es[s0] + edv;
            float e1 = es[s1] + edv;
            float e2 = es[s2] + edv;
            float e3 = es[s3] + edv;
            float e4 = es[s4] + edv;
            float e5 = es[s5] + edv;
            float e6 = es[s6] + edv;
            float e7 = es[s7] + edv;
            e0 = e0 > 0.f ? e0 : LEAKY * e0;  float x0 = __expf(e0);
            e1 = e1 > 0.f ? e1 : LEAKY * e1;  float x1 = __expf(e1);
            e2 = e2 > 0.f ? e2 : LEAKY * e2;  float x2 = __expf(e2);
            e3 = e3 > 0.f ? e3 : LEAKY * e3;  float x3 = __expf(e3);
            e4 = e4 > 0.f ? e4 : LEAKY * e4;  float x4 = __expf(e4);
            e5 = e5 > 0.f ? e5 : LEAKY * e5;  float x5 = __expf(e5);
            e6 = e6 > 0.f ? e6 : LEAKY * e6;  float x6 = __expf(e6);
            e7 = e7 > 0.f ? e7 : LEAKY * e7;  float x7 = __expf(e7);
            s += ((x0 + x1) + (x2 + x3)) + ((x4 + x5) + (x6 + x7));
            acc = fmaf(x0, h0, acc);
            acc = fmaf(x1, h1v, acc);
            acc = fmaf(x2, h2v, acc);
            acc = fmaf(x3, h3, acc);
            acc = fmaf(x4, h4, acc);
            acc = fmaf(x5, h5, acc);
            acc = fmaf(x6, h6, acc);
            acc = fmaf(x7, h7, acc);
        }
        for (; j + 4 <= cnt; j += 4) {
            int s0 = __shfl(myidx, j);
            int s1 = __shfl(myidx, j + 1);
            int s2 = __shfl(myidx, j + 2);
            int s3 = __shfl(myidx, j + 3);
            float h0 = pay ? h2[(size_t)s0 * 40 + l] : 0.f;
            float h1v = pay ? h2[(size_t)s1 * 40 + l] : 0.f;
            float h2v = pay ? h2[(size_t)s2 * 40 + l] : 0.f;
            float h3 = pay ? h2[(size_t)s3 * 40 + l] : 0.f;
            float e0 = es[s0] + edv;
            float e1 = es[s1] + edv;
            float e2 = es[s2] + edv;
            float e3 = es[s3] + edv;
            e0 = e0 > 0.f ? e0 : LEAKY * e0;  float x0 = __expf(e0);
            e1 = e1 > 0.f ? e1 : LEAKY * e1;  float x1 = __expf(e1);
            e2 = e2 > 0.f ? e2 : LEAKY * e2;  float x2 = __expf(e2);
            e3 = e3 > 0.f ? e3 : LEAKY * e3;  float x3 = __expf(e3);
            s += (x0 + x1) + (x2 + x3);
            acc = fmaf(x0, h0, acc);
            acc = fmaf(x1, h1v, acc);
            acc = fmaf(x2, h2v, acc);
            acc = fmaf(x3, h3, acc);
        }
        for (; j < cnt; ++j) {
            int s0 = __shfl(myidx, j);
            float h0 = pay ? h2[(size_t)s0 * 40 + l] : 0.f;
            float e0 = es[s0] + edv;
            e0 = e0 > 0.f ? e0 : LEAKY * e0;
            float x0 = __expf(e0);
            s += x0;
            acc = fmaf(x0, h0, acc);
        }
    }
    float v = acc / s + (pay ? b2[l] : 0.f);
    float mv = pay ? v : -1e30f;
    #pragma unroll
    for (int off = 1; off < 64; off <<= 1) mv = fmaxf(mv, __shfl_xor(mv, off));
    float ex = pay ? __expf(v - mv) : 0.f;
    #pragma unroll
    for (int off = 1; off < 64; off <<= 1) ex += __shfl_xor(ex, off);
    if (pay) out[(size_t)node * 40 + l] = v - mv - __logf(ex);
}

extern "C" void kernel_launch(void* const* d_in, const int* in_sizes, int n_in,
                              void* d_out, int out_size, void* d_ws, size_t ws_size,
                              hipStream_t stream) {
    const float* x   = (const float*)d_in[0];
    const int*   ei  = (const int*)d_in[1];
    const float* W1  = (const float*)d_in[2];
    const float* a1s = (const float*)d_in[3];
    const float* a1d = (const float*)d_in[4];
    const float* b1  = (const float*)d_in[5];
    const float* bng = (const float*)d_in[6];
    const float* bnb = (const float*)d_in[7];
    const float* bnm = (const float*)d_in[8];
    const float* bnv = (const float*)d_in[9];
    const float* W2  = (const float*)d_in[10];
    const float* a2s = (const float*)d_in[11];
    const float* a2d = (const float*)d_in[12];
    const float* b2  = (const float*)d_in[13];
    float* out = (float*)d_out;

    char* ws = (char*)d_ws;
    size_t off = 0;
    auto alloc = [&](size_t bytes) -> void* {
        void* p = ws + off;
        off = (off + bytes + 255) & ~(size_t)255;
        return p;
    };
    int*   cntb     = (int*)alloc((size_t)NB * NBB * 4);
    int*   excl     = (int*)alloc((size_t)NB * NBB * 4);
    int*   bsums    = (int*)alloc((size_t)NBB * 4);
    int*   offsets  = (int*)alloc((size_t)(NN + 1) * 4);
    u32*   packed   = (u32*)alloc((size_t)ETOT * 4);
    int*   ssrc     = (int*)alloc((size_t)ETOT * 4);
    u16*   Wt1      = (u16*)alloc((size_t)BN1 * 128 * 2);
    u16*   Wt2      = (u16*)alloc((size_t)BN2 * 128 * 2);
    u16*   h1b      = (u16*)alloc((size_t)NN * 128 * 2);
    float* es1      = (float*)alloc((size_t)NN * 4 * 4);
    float* ed1      = (float*)alloc((size_t)NN * 4 * 4);
    u16*   hbnb     = (u16*)alloc((size_t)NN * 128 * 2);
    float* h2       = (float*)alloc((size_t)NN * 40 * 4);
    float* es2      = (float*)alloc((size_t)NN * 4);
    float* ed2      = (float*)alloc((size_t)NN * 4);

    const int nscan = NB * NBB;  // 32768
    k_prep<<<80, 256, 0, stream>>>(W1, a1s, a1d, W2, a2s, a2d, Wt1, Wt2);
    k_binA<<<NBB, 256, 0, stream>>>(ei, cntb);
    k_scanA<<<nscan / 256, 256, 0, stream>>>(cntb, excl, bsums, nscan);
    k_scanB<<<1, 256, 0, stream>>>(bsums, NBB);
    k_scanC<<<nscan / 256, 256, 0, stream>>>(excl, bsums, nscan);
    k_binB<<<NBB, 256, 0, stream>>>(ei, excl, packed);
    k_binC<<<NB, 256, 0, stream>>>(packed, excl, offsets, ssrc);
    k_mm1<<<(NN + 127) / 128, 256, 0, stream>>>(x, Wt1, h1b, es1, ed1);
    k_agg1<<<(NN + 3) / 4, 256, 0, stream>>>(h1b, es1, ed1, offsets, ssrc,
                                             b1, bng, bnb, bnm, bnv, hbnb);
    k_mm2<<<(NN + 127) / 128, 256, 0, stream>>>(hbnb, Wt2, h2, es2, ed2);
    k_agg2<<<(NN + 3) / 4, 256, 0, stream>>>(h2, es2, ed2, offsets, ssrc, b2, out);
}